// Round 6
// baseline (258.789 us; speedup 1.0000x reference)
//
#include <hip/hip_runtime.h>
#include <hip/hip_bf16.h>

#define N_NODES 100000
#define N_EDGES 3200000

#define P_PARTS 7
#define PART    16384                    // 7*16384 = 114688 >= N; p = dst>>14
#define CBLOCKS 1024
#define EPB     (N_EDGES / CBLOCKS)      // 3125 exact
#define CHUNKS  64
#define HBLOCKS (P_PARTS * CHUNKS)       // 448
#define T_HIST  1024

// ---------------- workspace layout (bytes) ----------------
#define OFF_STATS   0         // double[5]          (zeroed)
#define OFF_CONST   64        // float[130]: A32,B32,C32,U32,GB,SCC
#define OFF_DEG     1024      // float[114688]      (zeroed)  [ends 459776]
#define OFF_ACC     459776    // float[114688]
#define OFF_DINV    918528    // float[100000]
#define OFF_GS      1318528   // float[100000]
#define OFF_BCNT    1718528   // int[1024*7]
#define OFF_BBASE   1747200   // int[1024*7]
#define OFF_PBASE   1775872   // int[8]
#define OFF_BUCKET  1775936   // uint[3200000]  [ends ~14.6 MB]

// per-wave int64-vs-int32 detection: high words of first 64 int64 slots
__device__ __forceinline__ bool detect_is64(const void* ei) {
    const int* p = (const int*)ei;
    int lane = threadIdx.x & 63;
    int hi = p[2 * lane + 1];
    unsigned long long m = __ballot(hi != 0);
    return m == 0ull;  // wave-uniform
}

// ---- K1: BN stats + per-block per-partition edge counts ----
__global__ __launch_bounds__(256) void count_stats_kernel(
        const float* __restrict__ x, const void* __restrict__ ei,
        double* __restrict__ stats, int* __restrict__ blockcnt) {
    __shared__ int cnt[P_PARTS];
    __shared__ double sh[5][4];
    if (threadIdx.x < P_PARTS) cnt[threadIdx.x] = 0;
    bool is64 = detect_is64(ei);

    // ---- stats: one node per thread (1024*256 >= N) ----
    {
        double a0 = 0, a1 = 0, a2 = 0, a3 = 0, a4 = 0;
        int n = blockIdx.x * 256 + threadIdx.x;
        if (n < N_NODES) {
            float2 v = ((const float2*)x)[n];
            double x0 = v.x, x1 = v.y;
            a0 = x0; a1 = x1; a2 = x0 * x0; a3 = x1 * x1; a4 = x0 * x1;
        }
        for (int off = 32; off; off >>= 1) {
            a0 += __shfl_down(a0, off);
            a1 += __shfl_down(a1, off);
            a2 += __shfl_down(a2, off);
            a3 += __shfl_down(a3, off);
            a4 += __shfl_down(a4, off);
        }
        int w = threadIdx.x >> 6;
        if ((threadIdx.x & 63) == 0) {
            sh[0][w] = a0; sh[1][w] = a1; sh[2][w] = a2; sh[3][w] = a3; sh[4][w] = a4;
        }
        __syncthreads();  // also covers cnt init
        if (threadIdx.x == 0) {
            double t0 = 0, t1 = 0, t2 = 0, t3 = 0, t4 = 0;
            for (int i = 0; i < 4; i++) {
                t0 += sh[0][i]; t1 += sh[1][i]; t2 += sh[2][i]; t3 += sh[3][i]; t4 += sh[4][i];
            }
            atomicAdd(&stats[0], t0);
            atomicAdd(&stats[1], t1);
            atomicAdd(&stats[2], t2);
            atomicAdd(&stats[3], t3);
            atomicAdd(&stats[4], t4);
        }
    }

    int e0 = blockIdx.x * EPB, e1 = e0 + EPB;
    if (is64) {
        const long long* dstp = (const long long*)ei + N_EDGES;
        for (int e = e0 + threadIdx.x; e < e1; e += 256)
            atomicAdd(&cnt[((int)dstp[e]) >> 14], 1);
    } else {
        const int* dstp = (const int*)ei + N_EDGES;
        for (int e = e0 + threadIdx.x; e < e1; e += 256)
            atomicAdd(&cnt[dstp[e] >> 14], 1);
    }
    __syncthreads();
    if (threadIdx.x < P_PARTS) blockcnt[blockIdx.x * P_PARTS + threadIdx.x] = cnt[threadIdx.x];
}

// ---- K2 (1 block): exact bucket bases via scan + encoder/head constants ----
__global__ __launch_bounds__(1024) void scan_consts_kernel(
        const int* __restrict__ blockcnt, int* __restrict__ blockbase, int* __restrict__ pbase,
        const double* __restrict__ stats,
        const float* __restrict__ w1, const float* __restrict__ b1,
        const float* __restrict__ gamma, const float* __restrict__ beta,
        const float* __restrict__ w2, const float* __restrict__ b2,
        const float* __restrict__ gcn_w, const float* __restrict__ wb,
        const float* __restrict__ gcn_b, const float* __restrict__ bb,
        float* __restrict__ consts) {
    __shared__ int wsum[16];
    __shared__ int tot[P_PARTS];
    __shared__ int pb[P_PARTS + 1];
    __shared__ float sV[32];
    int t = threadIdx.x;
    int lane = t & 63, w = t >> 6;
    int rx[P_PARTS];

    for (int p = 0; p < P_PARTS; p++) {
        int v = blockcnt[t * P_PARTS + p];
        // intra-wave inclusive scan
        int sv = v;
        for (int off = 1; off < 64; off <<= 1) {
            int u = __shfl_up(sv, off, 64);
            if (lane >= off) sv += u;
        }
        if (lane == 63) wsum[w] = sv;
        __syncthreads();
        if (w == 0) {
            int pv = (lane < 16) ? wsum[lane] : 0;
            for (int off = 1; off < 16; off <<= 1) {
                int u = __shfl_up(pv, off, 64);
                if (lane >= off) pv += u;
            }
            if (lane < 16) wsum[lane] = pv;
        }
        __syncthreads();
        int incl = sv + (w > 0 ? wsum[w - 1] : 0);
        rx[p] = incl - v;  // exclusive within column
        if (t == 1023) tot[p] = incl;
        __syncthreads();
    }
    if (t == 0) {
        int run = 0;
        for (int p = 0; p < P_PARTS; p++) { pb[p] = run; run += tot[p]; }
        pb[P_PARTS] = run;
        for (int p = 0; p <= P_PARTS; p++) pbase[p] = pb[p];
    }
    __syncthreads();
    for (int p = 0; p < P_PARTS; p++)
        blockbase[t * P_PARTS + p] = rx[p] + pb[p];

    // ---- constants (first 32 lanes of wave 0) ----
    if (t < 32) {
        int c = t;
        double invN = 1.0 / (double)N_NODES;
        double m0 = stats[0] * invN, m1 = stats[1] * invN;
        double e00 = stats[2] * invN, e11 = stats[3] * invN, e01 = stats[4] * invN;
        double a = w1[2 * c], b = w1[2 * c + 1], tt = b1[c];
        double meanH = a * m0 + b * m1 + tt;
        double eh2 = a * a * e00 + b * b * e11 + 2.0 * a * b * e01 +
                     2.0 * tt * (a * m0 + b * m1) + tt * tt;
        double var = eh2 - meanH * meanH;
        double inv = 1.0 / sqrt(var + 1e-5);
        float sc = (float)((double)gamma[c] * inv);
        float shift = beta[c] - (float)meanH * sc;
        consts[c]      = (float)a * sc;          // A
        consts[32 + c] = (float)b * sc;          // B
        consts[64 + c] = (float)tt * sc + shift; // C
        float vc = 0.f;
        for (int j = 0; j < 32; j++) vc += wb[j] * gcn_w[j * 32 + c];
        sV[c] = vc;
    }
    __syncthreads();
    if (t < 32) {
        float u = 0.f;
        for (int c = 0; c < 32; c++) u += sV[c] * w2[c * 32 + t];
        consts[96 + t] = u;                      // U
        float gb = b2[t] * sV[t];
        for (int off = 16; off; off >>= 1) gb += __shfl_down(gb, off, 32);
        float pv = wb[t] * gcn_b[t];
        for (int off = 16; off; off >>= 1) pv += __shfl_down(pv, off, 32);
        if (t == 0) {
            consts[128] = gb;                    // GB = b2 . v
            consts[129] = pv + bb[0];            // SCC
        }
    }
}

// ---- K3: compact edges into partition buckets, packed u32 ----
__global__ __launch_bounds__(256) void compact_kernel(
        const void* __restrict__ ei, const int* __restrict__ blockbase,
        unsigned* __restrict__ bucket) {
    __shared__ int rank[P_PARTS];
    __shared__ int bbase[P_PARTS];
    if (threadIdx.x < P_PARTS) {
        rank[threadIdx.x] = 0;
        bbase[threadIdx.x] = blockbase[blockIdx.x * P_PARTS + threadIdx.x];
    }
    bool is64 = detect_is64(ei);
    __syncthreads();
    int e0 = blockIdx.x * EPB, e1 = e0 + EPB;
    if (is64) {
        const long long* srcp = (const long long*)ei;
        const long long* dstp = srcp + N_EDGES;
        for (int e = e0 + threadIdx.x; e < e1; e += 256) {
            int s = (int)srcp[e];
            int d = (int)dstp[e];
            int p = d >> 14;
            unsigned packed = (unsigned)s | ((unsigned)(d & 16383) << 17);
            int pos = bbase[p] + atomicAdd(&rank[p], 1);
            bucket[pos] = packed;
        }
    } else {
        const int* srcp = (const int*)ei;
        const int* dstp = srcp + N_EDGES;
        for (int e = e0 + threadIdx.x; e < e1; e += 256) {
            int s = srcp[e];
            int d = dstp[e];
            int p = d >> 14;
            unsigned packed = (unsigned)s | ((unsigned)(d & 16383) << 17);
            int pos = bbase[p] + atomicAdd(&rank[p], 1);
            bucket[pos] = packed;
        }
    }
}

// ---- K4: degree histogram from buckets (single-read) ----
__global__ __launch_bounds__(T_HIST, 2) void deg_hist_kernel(
        const unsigned* __restrict__ bucket, const int* __restrict__ pbase,
        float* __restrict__ degf) {
    __shared__ float hist[PART];
    int p = blockIdx.x % P_PARTS;
    int chunk = blockIdx.x / P_PARTS;
    for (int i = threadIdx.x; i < PART; i += T_HIST) hist[i] = 0.f;
    int b0 = pbase[p], b1 = pbase[p + 1];
    int cnt = b1 - b0;
    int per = (cnt + CHUNKS - 1) / CHUNKS;
    int lo = b0 + chunk * per;
    int hi = min(lo + per, b1);
    __syncthreads();
    for (int i = lo + threadIdx.x; i < hi; i += T_HIST)
        atomicAdd(&hist[bucket[i] >> 17], 1.0f);
    __syncthreads();
    int base = p << 14;
    for (int i = threadIdx.x; i < PART; i += T_HIST) {
        float v = hist[i];
        if (v != 0.f) unsafeAtomicAdd(&degf[base + i], v);
    }
}

// ---- K5: encoder (scalar): gs[n] = dinv * (GB + sum_c PReLU(Ax0+Bx1+C) U[c]) ----
__global__ void encoder_kernel(const float* __restrict__ x, const float* __restrict__ consts,
                               const float* __restrict__ prelu_a, const float* __restrict__ degf,
                               float* __restrict__ dinv, float* __restrict__ gs,
                               float* __restrict__ acc) {
    __shared__ float sA[32], sB[32], sC[32], sU[32];
    __shared__ float sGB;
    if (threadIdx.x < 32) {
        sA[threadIdx.x] = consts[threadIdx.x];
        sB[threadIdx.x] = consts[32 + threadIdx.x];
        sC[threadIdx.x] = consts[64 + threadIdx.x];
        sU[threadIdx.x] = consts[96 + threadIdx.x];
    }
    if (threadIdx.x == 0) sGB = consts[128];
    __syncthreads();
    float alpha = prelu_a[0];
    int n = blockIdx.x * blockDim.x + threadIdx.x;
    if (n < N_NODES) {
        float2 xv = ((const float2*)x)[n];
        float g = sGB;
#pragma unroll
        for (int c = 0; c < 32; c++) {
            float hb = sA[c] * xv.x + sB[c] * xv.y + sC[c];
            float pc = hb >= 0.f ? hb : alpha * hb;
            g += pc * sU[c];
        }
        float di = rsqrtf(degf[n] + 1.0f);
        float gg = di * g;
        dinv[n] = di;
        gs[n] = gg;
        acc[n] = gg;  // self-loop term; finalize multiplies by dinv
    }
}

// ---- K6: scatter from buckets (single-read) ----
__global__ __launch_bounds__(T_HIST, 2) void scatter_hist_kernel(
        const unsigned* __restrict__ bucket, const int* __restrict__ pbase,
        const float* __restrict__ gs, float* __restrict__ acc) {
    __shared__ float hist[PART];
    int p = blockIdx.x % P_PARTS;
    int chunk = blockIdx.x / P_PARTS;
    for (int i = threadIdx.x; i < PART; i += T_HIST) hist[i] = 0.f;
    int b0 = pbase[p], b1 = pbase[p + 1];
    int cnt = b1 - b0;
    int per = (cnt + CHUNKS - 1) / CHUNKS;
    int lo = b0 + chunk * per;
    int hi = min(lo + per, b1);
    __syncthreads();
    for (int i = lo + threadIdx.x; i < hi; i += T_HIST) {
        unsigned pk = bucket[i];
        atomicAdd(&hist[pk >> 17], gs[pk & 0x1FFFF]);
    }
    __syncthreads();
    int base = p << 14;
    for (int i = threadIdx.x; i < PART; i += T_HIST) {
        float v = hist[i];
        if (v != 0.f) unsafeAtomicAdd(&acc[base + i], v);
    }
}

// ---- K7: finalize ----
__global__ void finalize_kernel(const float* __restrict__ dinv, const float* __restrict__ acc,
                                const float* __restrict__ consts, float* __restrict__ out) {
    int n = blockIdx.x * blockDim.x + threadIdx.x;
    if (n < N_NODES) out[n] = dinv[n] * acc[n] + consts[129];
}

extern "C" void kernel_launch(void* const* d_in, const int* in_sizes, int n_in,
                              void* d_out, int out_size, void* d_ws, size_t ws_size,
                              hipStream_t stream) {
    const float* x       = (const float*)d_in[0];
    const void*  ei      = d_in[1];
    const float* w1      = (const float*)d_in[2];
    const float* b1      = (const float*)d_in[3];
    const float* bn_g    = (const float*)d_in[4];
    const float* bn_b    = (const float*)d_in[5];
    const float* prelu_a = (const float*)d_in[6];
    const float* w2      = (const float*)d_in[7];
    const float* b2      = (const float*)d_in[8];
    const float* gcn_w   = (const float*)d_in[9];
    const float* gcn_b   = (const float*)d_in[10];
    const float* wb      = (const float*)d_in[11];
    const float* bb      = (const float*)d_in[12];
    float* out = (float*)d_out;

    char* base = (char*)d_ws;
    double*   stats  = (double*)(base + OFF_STATS);
    float*    consts = (float*)(base + OFF_CONST);
    float*    degf   = (float*)(base + OFF_DEG);
    float*    acc    = (float*)(base + OFF_ACC);
    float*    dinv   = (float*)(base + OFF_DINV);
    float*    gs     = (float*)(base + OFF_GS);
    int*      bcnt   = (int*)(base + OFF_BCNT);
    int*      bbase  = (int*)(base + OFF_BBASE);
    int*      pbase  = (int*)(base + OFF_PBASE);
    unsigned* bucket = (unsigned*)(base + OFF_BUCKET);

    // zero stats + consts + degf
    hipMemsetAsync(d_ws, 0, OFF_DEG + PART * P_PARTS * 4, stream);

    count_stats_kernel<<<CBLOCKS, 256, 0, stream>>>(x, ei, stats, bcnt);
    scan_consts_kernel<<<1, 1024, 0, stream>>>(bcnt, bbase, pbase, stats,
        w1, b1, bn_g, bn_b, w2, b2, gcn_w, wb, gcn_b, bb, consts);
    compact_kernel<<<CBLOCKS, 256, 0, stream>>>(ei, bbase, bucket);
    deg_hist_kernel<<<HBLOCKS, T_HIST, 0, stream>>>(bucket, pbase, degf);
    encoder_kernel<<<(N_NODES + 255) / 256, 256, 0, stream>>>(
        x, consts, prelu_a, degf, dinv, gs, acc);
    scatter_hist_kernel<<<HBLOCKS, T_HIST, 0, stream>>>(bucket, pbase, gs, acc);
    finalize_kernel<<<(N_NODES + 255) / 256, 256, 0, stream>>>(dinv, acc, consts, out);
}